// Round 1
// baseline (1759.973 us; speedup 1.0000x reference)
//
#include <hip/hip_runtime.h>

#define TT 512   // max sequence length T
#define NN 128   // number of tags N

// One block per batch element. 128 threads = 2 waves; thread j owns tag j.
// trans column j lives in 128 VGPRs; state double-buffered in LDS; bp in LDS.
__global__ __launch_bounds__(128, 1)
void crf_viterbi_kernel(const float* __restrict__ logits,
                        const float* __restrict__ trans,
                        const int* __restrict__ seqlen,
                        int* __restrict__ out) {
    __shared__ float stateBuf[2][NN];
    __shared__ float redV[NN];
    __shared__ int   redI[NN];
    __shared__ int   tagBuf[TT];
    __shared__ unsigned char bp[TT][NN];  // row t = backpointers of forward step t (1..L-1)

    const int b = blockIdx.x;
    const int j = threadIdx.x;   // 0..127
    const int L = seqlen[b];     // in [1, TT]

    // Load transitions column j into registers: tr[i] = trans[i][j].
    // Coalesced across lanes per i; cached in L2/L3 after first blocks.
    float tr[NN];
    #pragma unroll
    for (int i = 0; i < NN; ++i) tr[i] = trans[i * NN + j];

    const float* lrow = logits + (size_t)b * TT * NN;

    // t = 0 init
    float sval = lrow[j];
    stateBuf[0][j] = sval;
    __syncthreads();

    int p = 0;
    float x_cur = lrow[NN + j];  // row t=1 always in-bounds (T=512 rows allocated)
    for (int t = 1; t < L; ++t) {
        // Prefetch next logits row (clamped address; value unused on last iter).
        int tn = (t + 1 < L) ? (t + 1) : (L - 1);
        float x_next = lrow[tn * NN + j];

        const float* st = stateBuf[p];
        float best = -__builtin_inff();
        int arg = 0;
        #pragma unroll
        for (int i4 = 0; i4 < NN / 4; ++i4) {
            // All lanes read the same address -> LDS broadcast, conflict-free.
            float4 s4 = *(const float4*)(st + i4 * 4);
            float ss[4] = {s4.x, s4.y, s4.z, s4.w};
            #pragma unroll
            for (int u = 0; u < 4; ++u) {
                float sc = ss[u] + tr[i4 * 4 + u];
                // strict > over ascending i == jnp.argmax first-occurrence
                if (sc > best) { best = sc; arg = i4 * 4 + u; }
            }
        }
        sval = best + x_cur;
        stateBuf[p ^ 1][j] = sval;           // write other buffer: no read/write race
        bp[t][j] = (unsigned char)arg;
        x_cur = x_next;
        __syncthreads();                     // single barrier per step (double buffer)
        p ^= 1;
    }

    // argmax over final state (first-occurrence tie-break: prefer smaller index)
    redV[j] = sval;
    redI[j] = j;
    __syncthreads();
    #pragma unroll
    for (int off = 64; off >= 1; off >>= 1) {
        if (j < off) {
            float va = redV[j], vb = redV[j + off];
            int   ia = redI[j], ib = redI[j + off];
            if (vb > va || (vb == va && ib < ia)) { redV[j] = vb; redI[j] = ib; }
        }
        __syncthreads();
    }

    // Backtrack: sequential LDS pointer-chase by thread 0.
    if (j == 0) {
        int cur = redI[0];
        tagBuf[L - 1] = cur;
        for (int t = L - 1; t >= 1; --t) {
            cur = bp[t][cur];
            tagBuf[t - 1] = cur;
        }
    }
    __syncthreads();

    // Coalesced output: tags for k < L, zeros for the masked tail.
    int* orow = out + (size_t)b * TT;
    #pragma unroll
    for (int k = j; k < TT; k += NN) {
        orow[k] = (k < L) ? tagBuf[k] : 0;
    }
}

extern "C" void kernel_launch(void* const* d_in, const int* in_sizes, int n_in,
                              void* d_out, int out_size, void* d_ws, size_t ws_size,
                              hipStream_t stream) {
    const float* logits = (const float*)d_in[0];
    const float* trans  = (const float*)d_in[1];
    const int*   seqlen = (const int*)d_in[2];
    int*         out    = (int*)d_out;
    const int B = in_sizes[2];  // 256
    crf_viterbi_kernel<<<B, NN, 0, stream>>>(logits, trans, seqlen, out);
}

// Round 2
// 507.817 us; speedup vs baseline: 3.4658x; 3.4658x over previous
//
#include <hip/hip_runtime.h>

#define TT 512   // max sequence length T
#define NN 128   // number of tags N
#define NTHR 512 // 8 waves: lane quads share an output tag j; each lane owns 32 i's

// One block per batch element (256 blocks <-> 256 CUs).
// thread -> (j, c): j = 16*wave + (lane>>2), c = lane&3, i-range [32c, 32c+32).
// trans chunk (32 regs) per thread; state double-buffered in LDS (broadcast
// float4 reads); quad argmax combined with in-wave shfl_xor (no extra barrier);
// backpointers in LDS; one __syncthreads per step.
__global__ __launch_bounds__(NTHR, 1)
void crf_viterbi_kernel(const float* __restrict__ logits,
                        const float* __restrict__ trans,
                        const int* __restrict__ seqlen,
                        int* __restrict__ out) {
    __shared__ float stateBuf[2][NN];
    __shared__ float redV[NN];
    __shared__ int   redI[NN];
    __shared__ int   tagBuf[TT];
    __shared__ unsigned char bp[TT][NN];

    const int tid = threadIdx.x;
    const int lane = tid & 63;
    const int wv   = tid >> 6;
    const int j    = (wv << 4) | (lane >> 2);  // 0..127, shared by the lane quad
    const int c    = lane & 3;                 // i-chunk id
    const int i0   = c << 5;                   // 32*c
    const int b = blockIdx.x;
    const int L = seqlen[b];                   // in [1, TT]

    // Per-thread transitions chunk: tr[k] = trans[i0+k][j]  (32 VGPRs, no spill)
    float tr[32];
    #pragma unroll
    for (int k = 0; k < 32; ++k) tr[k] = trans[(i0 + k) * NN + j];

    const float* lrow = logits + (size_t)b * TT * NN;

    // t = 0 init
    if (c == 0) stateBuf[0][j] = lrow[j];
    __syncthreads();

    int p = 0;
    float x_cur = lrow[NN + j];  // row t=1 (always allocated; unused if L==1)
    for (int t = 1; t < L; ++t) {
        // software-pipelined logits prefetch (clamped addr; dup lanes coalesce)
        int tn = (t + 1 < L) ? (t + 1) : (L - 1);
        float x_next = lrow[tn * NN + j];

        // issue all 8 broadcast float4 state reads up-front (ILP)
        const float4* st4 = (const float4*)(stateBuf[p] + i0);
        float4 s4[8];
        #pragma unroll
        for (int q = 0; q < 8; ++q) s4[q] = st4[q];

        // 32-long scan: strict > over ascending i == first-occurrence argmax
        float best = -__builtin_inff();
        int arg = 0;
        #pragma unroll
        for (int q = 0; q < 8; ++q) {
            float ss[4] = {s4[q].x, s4[q].y, s4[q].z, s4[q].w};
            #pragma unroll
            for (int u = 0; u < 4; ++u) {
                float sc = ss[u] + tr[q * 4 + u];
                bool g = sc > best;
                best = g ? sc : best;
                arg  = g ? (i0 + q * 4 + u) : arg;
            }
        }

        // combine the 4 chunk-partials within the lane quad (same j).
        // tie-break: smaller global i wins (exact reference semantics).
        #pragma unroll
        for (int m = 1; m <= 2; m <<= 1) {
            float pv = __shfl_xor(best, m, 64);
            int   pi = __shfl_xor(arg,  m, 64);
            bool take = (pv > best) || (pv == best && pi < arg);
            best = take ? pv : best;
            arg  = take ? pi : arg;
        }

        if (c == 0) {
            stateBuf[p ^ 1][j] = best + x_cur;   // write other buffer: no race
            bp[t][j] = (unsigned char)arg;
        }
        x_cur = x_next;
        __syncthreads();                         // single barrier per step
        p ^= 1;
    }

    // argmax over final state (first-occurrence tie-break: smaller index)
    if (tid < NN) { redV[tid] = stateBuf[p][tid]; redI[tid] = tid; }
    __syncthreads();
    #pragma unroll
    for (int off = 64; off >= 1; off >>= 1) {
        if (tid < off) {
            float va = redV[tid], vb = redV[tid + off];
            int   ia = redI[tid], ib = redI[tid + off];
            if (vb > va || (vb == va && ib < ia)) { redV[tid] = vb; redI[tid] = ib; }
        }
        __syncthreads();
    }

    // Backtrack: sequential LDS pointer-chase by thread 0.
    if (tid == 0) {
        int cur = redI[0];
        tagBuf[L - 1] = cur;
        for (int t = L - 1; t >= 1; --t) {
            cur = bp[t][cur];
            tagBuf[t - 1] = cur;
        }
    }
    __syncthreads();

    // Coalesced output: tags for k < L, zeros for the masked tail.
    int* orow = out + (size_t)b * TT;
    orow[tid] = (tid < L) ? tagBuf[tid] : 0;
}

extern "C" void kernel_launch(void* const* d_in, const int* in_sizes, int n_in,
                              void* d_out, int out_size, void* d_ws, size_t ws_size,
                              hipStream_t stream) {
    const float* logits = (const float*)d_in[0];
    const float* trans  = (const float*)d_in[1];
    const int*   seqlen = (const int*)d_in[2];
    int*         out    = (int*)d_out;
    const int B = in_sizes[2];  // 256
    crf_viterbi_kernel<<<B, NTHR, 0, stream>>>(logits, trans, seqlen, out);
}